// Round 5
// baseline (499.964 us; speedup 1.0000x reference)
//
#include <hip/hip_runtime.h>

#define DEVINL __device__ __forceinline__

typedef __attribute__((ext_vector_type(8))) short short8;
typedef __attribute__((ext_vector_type(4))) float floatx4;
typedef __attribute__((ext_vector_type(2))) unsigned uintx2;

DEVINL unsigned short f2bf(float f){
  unsigned u = __builtin_bit_cast(unsigned, f);
  u += 0x7FFFu + ((u >> 16) & 1u);          // RNE
  return (unsigned short)(u >> 16);
}
DEVINL unsigned pk2(float a, float b){      // low16=bf16(a), high16=bf16(b)
  unsigned ua = __builtin_bit_cast(unsigned, a);
  unsigned ub = __builtin_bit_cast(unsigned, b);
  ua += 0x7FFFu + ((ua >> 16) & 1u);
  ub += 0x7FFFu + ((ub >> 16) & 1u);
  return (ua >> 16) | (ub & 0xFFFF0000u);
}
// round-half-up bf16 pack of (a,b) via v_perm (proven numerics; do NOT use
// v_cvt_pk_bf16_f32 here -- it truncates and fails the absmax threshold)
DEVINL unsigned pkfast(float a, float b){
  unsigned ua = __builtin_bit_cast(unsigned, a) + 0x8000u;
  unsigned ub = __builtin_bit_cast(unsigned, b) + 0x8000u;
  return __builtin_amdgcn_perm(ub, ua, 0x07060302u);
}
DEVINL float bf2f(unsigned short h){
  unsigned u = ((unsigned)h) << 16;
  return __builtin_bit_cast(float, u);
}
DEVINL void gload_lds16(const void* g, void* l){
  __builtin_amdgcn_global_load_lds((const __attribute__((address_space(1))) void*)g,
                                   (__attribute__((address_space(3))) void*)l, 16, 0, 0);
}
// key permutation: St C-layout register <-> PV B-operand k' index
DEVINL int perm2(int k){
  return (((k >> 4) & 1) << 5) | (((k >> 2) & 3) << 3) | (((k >> 5) & 1) << 2) | (k & 3);
}

// ---------------- dtype detector ----------------
__global__ void k_detect(const unsigned* __restrict__ w, int* __restrict__ flag){
  __shared__ int cnt;
  if (threadIdx.x == 0) cnt = 0;
  __syncthreads();
  int c = 0;
  for (int i = threadIdx.x; i < 1024; i += 256){
    unsigned e = (w[i] >> 7) & 0xFFu;
    c += (e >= 120u && e <= 132u) ? 1 : 0;
  }
  atomicAdd(&cnt, c);
  __syncthreads();
  if (threadIdx.x == 0) *flag = (cnt > 512) ? 1 : 0;
}

// ---------------- conversions ----------------
__global__ void k_conv_bf16(const void* __restrict__ src, unsigned short* __restrict__ dst,
                            int n, const int* __restrict__ flag){
  int i = (blockIdx.x * 256 + threadIdx.x) * 8;
  if (i >= n) return;
  if (*flag){
    ((uint4*)dst)[i >> 3] = ((const uint4*)src)[i >> 3];
  } else {
    const float* s = (const float*)src;
    short8 v;
    #pragma unroll
    for (int j = 0; j < 8; j++) v[j] = (short)f2bf(s[i + j]);
    *(short8*)(dst + i) = v;
  }
}

// 4 weights [K][N] -> [N][K] bf16, one launch (z selects matrix)
__global__ void k_conv_wT4(const void* __restrict__ s0, const void* __restrict__ s1,
                           const void* __restrict__ s2, const void* __restrict__ s3,
                           unsigned short* __restrict__ d0, unsigned short* __restrict__ d1,
                           unsigned short* __restrict__ d2, unsigned short* __restrict__ d3,
                           const int* __restrict__ flag){
  __shared__ float tile[32][33];
  const void* src; unsigned short* dst;
  switch (blockIdx.z){
    case 0: src = s0; dst = d0; break;
    case 1: src = s1; dst = d1; break;
    case 2: src = s2; dst = d2; break;
    default: src = s3; dst = d3; break;
  }
  const int tx = threadIdx.x & 31, ty = threadIdx.x >> 5;
  const int bx = blockIdx.x, by = blockIdx.y;
  const int isbf = *flag;
  #pragma unroll
  for (int r = 0; r < 32; r += 8){
    int k = by*32 + ty + r, n = bx*32 + tx;
    float v = isbf ? bf2f(((const unsigned short*)src)[k*1024 + n])
                   : ((const float*)src)[k*1024 + n];
    tile[ty + r][tx] = v;
  }
  __syncthreads();
  #pragma unroll
  for (int r = 0; r < 32; r += 8){
    int n = bx*32 + ty + r, k = by*32 + tx;
    dst[n*1024 + k] = f2bf(tile[tx][ty + r]);
  }
}

// 4 biases -> one contiguous float[4096]
__global__ void k_conv_b4(const void* __restrict__ s0, const void* __restrict__ s1,
                          const void* __restrict__ s2, const void* __restrict__ s3,
                          float* __restrict__ dst, const int* __restrict__ flag){
  int i = blockIdx.x * 256 + threadIdx.x;
  if (i >= 4096) return;
  int z = i >> 10, j = i & 1023;
  const void* s = (z == 0) ? s0 : (z == 1) ? s1 : (z == 2) ? s2 : s3;
  dst[i] = (*flag) ? bf2f(((const unsigned short*)s)[j]) : ((const float*)s)[j];
}

// ---------------- m97-style bf16 GEMM, A[M,K] x Bt[N,K]^T + bias ----------------
// MODE 3: fused QKV, N=3072. n>>10 selects dst:
//   0 -> Q [h][s][d^sw] (*scale)   1 -> K [h][s][d^sw]   2 -> V [h][d][s'^sw] (key-permuted)
//   where ^sw = XOR of the 16B-chunk index with (row&7) -- pre-swizzled for LDS.
// MODE 1: dst = C0, [m][n]; fp32 or bf16 per *flagp
template<int MODE>
__global__ __launch_bounds__(256, 2) void k_gemm(
    const unsigned short* __restrict__ A, const unsigned short* __restrict__ Bt,
    const float* __restrict__ bias, void* __restrict__ C0, void* __restrict__ C1,
    void* __restrict__ C2, const int* __restrict__ flagp, float scale)
{
  const int K = 1024;
  __shared__ __align__(16) unsigned short As[128*32];
  __shared__ __align__(16) unsigned short Bs[128*32];
  const int tid = threadIdx.x;
  const int lane = tid & 63, wave = tid >> 6;
  const int quad = lane >> 4, l15 = lane & 15;
  const int m0 = blockIdx.x * 128, n0 = blockIdx.y * 128;
  const int wm = (wave >> 1) * 64, wn = (wave & 1) * 64;
  const floatx4 fzero = {0.f, 0.f, 0.f, 0.f};
  floatx4 acc[4][4];
  #pragma unroll
  for (int i = 0; i < 4; i++)
    #pragma unroll
    for (int j = 0; j < 4; j++) acc[i][j] = fzero;

  for (int k0 = 0; k0 < K; k0 += 32){
    __syncthreads();
    #pragma unroll
    for (int rep = 0; rep < 2; rep++){
      int idx = tid + rep*256;
      int row = idx >> 2, c = idx & 3;
      gload_lds16(A  + (size_t)(m0 + row)*K + (k0 + c*8), &As[idx*8]);
      gload_lds16(Bt + (size_t)(n0 + row)*K + (k0 + c*8), &Bs[idx*8]);
    }
    asm volatile("s_waitcnt vmcnt(0)" ::: "memory");
    __syncthreads();
    short8 af[4], bf[4];
    #pragma unroll
    for (int i = 0; i < 4; i++) af[i] = *(const short8*)&As[(wm + i*16 + l15)*32 + quad*8];
    #pragma unroll
    for (int j = 0; j < 4; j++) bf[j] = *(const short8*)&Bs[(wn + j*16 + l15)*32 + quad*8];
    #pragma unroll
    for (int i = 0; i < 4; i++)
      #pragma unroll
      for (int j = 0; j < 4; j++)
        acc[i][j] = __builtin_amdgcn_mfma_f32_16x16x32_bf16(af[i], bf[j], acc[i][j], 0, 0, 0);
  }

  float bs[4];
  #pragma unroll
  for (int j = 0; j < 4; j++) bs[j] = bias[n0 + wn + j*16 + l15];
  const int useBf = (MODE == 1) ? *flagp : 1;
  #pragma unroll
  for (int i = 0; i < 4; i++){
    #pragma unroll
    for (int j = 0; j < 4; j++){
      int n = n0 + wn + j*16 + l15;
      #pragma unroll
      for (int r = 0; r < 4; r++){
        int m = m0 + wm + i*16 + quad*4 + r;      // C/D: col=lane&15, row=quad*4+reg
        float v = acc[i][j][r] + bs[j];
        if (MODE == 3){
          int sel = n >> 10, nn = n & 1023;       // wave-uniform per (i,j)
          if (sel == 0){
            int dd = (nn & 63) ^ ((m & 7) << 3);  // pre-swizzle chunk by s&7
            ((unsigned short*)C0)[((size_t)(nn >> 6)*8192 + m)*64 + dd] = f2bf(v * scale);
          } else if (sel == 1){
            int dd = (nn & 63) ^ ((m & 7) << 3);
            ((unsigned short*)C1)[((size_t)(nn >> 6)*8192 + m)*64 + dd] = f2bf(v);
          } else {
            int s2 = perm2(m & 63) ^ ((nn & 7) << 3);  // key-perm then swizzle by d&7
            ((unsigned short*)C2)[(size_t)nn*8192 + (m & ~63) + s2] = f2bf(v);
          }
        } else {
          if (useBf) ((unsigned short*)C0)[(size_t)m*1024 + n] = f2bf(v);
          else       ((float*)C0)[(size_t)m*1024 + n] = v;
        }
      }
    }
  }
}

// ---------------- ring attention: 256q block, 64q/wave, fused per-mi pipeline ----------
// Changes vs the 311us two-phase version:
//  * PV fused into the mi loop (QK(mi+1) independent of exp/PV(mi) -> MFMA/VALU co-issue
//    within one wave; pf state 32->8 regs).
//  * kt loop unrolled x2 so `cur` is static; all K/V/Q fragment reads become
//    per-lane-base + ds_read immediate offset (row&7 == l15&7 for all rows).
//  * row-sum moved off the MFMA pipe: in-lane 16-add tree per mi per tile, quad-reduce
//    via 2x shfl_xor once per chunk (replaces 8 ones-MFMA/tile, frees Ol/ones regs).
//  * V fragments hoisted per tile (8 reads reused by 4 mi); Q re-read per mi from LDS.
//  * no setprio (R4: neutral/harmful).
__global__ __launch_bounds__(256, 2) void k_attn(
    const unsigned short* __restrict__ Qg, const unsigned short* __restrict__ Kg,
    const unsigned short* __restrict__ Vg, unsigned short* __restrict__ ctx)
{
  __shared__ __align__(16) unsigned short Qs[256*64];       // 32KB
  __shared__ __align__(16) unsigned short KV[2*64*64*2];    // K bufs [0,16KB), V bufs [16KB,32KB)
  const int tid = threadIdx.x, lane = tid & 63, wave = tid >> 6;
  const int quad = lane >> 4, l15 = lane & 15;
  const int bid = blockIdx.x;
  const int xcd = bid & 7, slot = bid >> 3;
  const int h = xcd*2 + (slot >> 5);
  const int rem = slot & 31, rchunk = rem >> 3, qt = rem & 7;
  const int sq0 = rchunk*2048 + qt*256;
  const char* Qbase = (const char*)(Qg + (size_t)h*8192*64 + (size_t)sq0*64);
  const char* Kbase = (const char*)(Kg + (size_t)h*8192*64);     // [s][d^sw] rows 128B
  const char* Vbase = (const char*)(Vg + (size_t)h*8192*64);     // [d][s'^sw] rows 16KB
  const int wq0 = wave * 64;
  const floatx4 fzero = {0.f, 0.f, 0.f, 0.f};

  // per-thread fixed staging offsets
  const int idx0 = tid, idx1 = tid + 256;
  const size_t voff0 = (size_t)(idx0 >> 3)*16384 + (idx0 & 7)*16;
  const size_t voff1 = (size_t)(idx1 >> 3)*16384 + (idx1 & 7)*16;

  auto stage = [&](int buf, int kvs){
    const char* Kt = Kbase + (size_t)kvs*128;
    const char* Vt = Vbase + (size_t)kvs*2;
    char* kd = (char*)KV + buf*8192;
    char* vd = (char*)KV + 16384 + buf*8192;
    gload_lds16(Kt + idx0*16, kd + idx0*16);
    gload_lds16(Kt + idx1*16, kd + idx1*16);
    gload_lds16(Vt + voff0, vd + idx0*16);
    gload_lds16(Vt + voff1, vd + idx1*16);
  };

  // stage Q (straight 32KB copy) + first K/V tile
  #pragma unroll
  for (int rep = 0; rep < 8; rep++){
    int idx = tid + rep*256;
    gload_lds16(Qbase + idx*16, (char*)Qs + idx*16);
  }
  stage(0, rchunk*2048);

  // per-lane LDS base addresses; every fragment read is base + constant offset.
  // row&7 == l15&7 for all K/V/Q fragment rows (row = {ni,di,mi}*16 + l15, wq0%8==0).
  const int swz0 = ((0*4 + quad) ^ (l15 & 7)) * 16;
  const int swz1 = ((1*4 + quad) ^ (l15 & 7)) * 16;
  const char* kvb0 = (const char*)KV + l15*128 + swz0;     // + cur*8192 + ni*2048  (K)
  const char* kvb1 = (const char*)KV + l15*128 + swz1;     //   +16384 ... (V)
  const char* qb0  = (const char*)Qs + (wq0 + l15)*128 + swz0;  // + mi*2048
  const char* qb1  = (const char*)Qs + (wq0 + l15)*128 + swz1;

  asm volatile("s_waitcnt vmcnt(0)" ::: "memory");
  __syncthreads();

  floatx4 Of[4][4];
  #pragma unroll
  for (int mi = 0; mi < 4; mi++)
    #pragma unroll
    for (int di = 0; di < 4; di++) Of[mi][di] = fzero;

// one K/V tile with static buffer parity CUR
#define TILE_BODY(CUR, TT)                                                          \
  {                                                                                 \
    asm volatile("s_waitcnt vmcnt(0)" ::: "memory");  /* tile TT landed */          \
    __syncthreads();                                  /* prev readers done */       \
    if ((TT) < 127){                                                                \
      int t1 = (TT) + 1;                                                            \
      int kvs = ((rchunk + (t1 >> 5)) & 3)*2048 + (t1 & 31)*64;                     \
      stage((CUR) ^ 1, kvs);                          /* async, lands in compute */ \
    }                                                                               \
    short8 vf[2][4];                                                                \
    _Pragma("unroll")                                                               \
    for (int di = 0; di < 4; di++){                                                 \
      vf[0][di] = *(const short8*)(kvb0 + (16384 + (CUR)*8192) + di*2048);          \
      vf[1][di] = *(const short8*)(kvb1 + (16384 + (CUR)*8192) + di*2048);          \
    }                                                                               \
    _Pragma("unroll")                                                               \
    for (int mi = 0; mi < 4; mi++){                                                 \
      short8 q0 = *(const short8*)(qb0 + mi*2048);                                  \
      short8 q1 = *(const short8*)(qb1 + mi*2048);                                  \
      floatx4 St[4];                                                                \
      _Pragma("unroll")                                                             \
      for (int ni = 0; ni < 4; ni++) St[ni] = fzero;                                \
      _Pragma("unroll")                                                             \
      for (int ni = 0; ni < 4; ni++){                                               \
        short8 kf0 = *(const short8*)(kvb0 + (CUR)*8192 + ni*2048);                 \
        short8 kf1 = *(const short8*)(kvb1 + (CUR)*8192 + ni*2048);                 \
        St[ni] = __builtin_amdgcn_mfma_f32_16x16x32_bf16(kf0, q0, St[ni], 0, 0, 0); \
        St[ni] = __builtin_amdgcn_mfma_f32_16x16x32_bf16(kf1, q1, St[ni], 0, 0, 0); \
      }                                                                             \
      _Pragma("unroll")                                                             \
      for (int ni = 0; ni < 4; ni++)                                                \
        _Pragma("unroll")                                                           \
        for (int r = 0; r < 4; r++)                                                 \
          St[ni][r] = __builtin_amdgcn_exp2f(St[ni][r]);                            \
      {                                                                             \
        float t0 = (St[0][0] + St[0][1]) + (St[0][2] + St[0][3]);                   \
        float t1 = (St[1][0] + St[1][1]) + (St[1][2] + St[1][3]);                   \
        float t2 = (St[2][0] + St[2][1]) + (St[2][2] + St[2][3]);                   \
        float t3 = (St[3][0] + St[3][1]) + (St[3][2] + St[3][3]);                   \
        Olp[mi] += (t0 + t2) + (t1 + t3);                                           \
      }                                                                             \
      short8 pf0, pf1;                                                              \
      {                                                                             \
        uintx2 lo, hi;                                                              \
        union { uintx2 u[2]; short8 s; } cv;                                        \
        lo[0] = pkfast(St[0][0], St[0][1]); lo[1] = pkfast(St[0][2], St[0][3]);     \
        hi[0] = pkfast(St[2][0], St[2][1]); hi[1] = pkfast(St[2][2], St[2][3]);     \
        cv.u[0] = lo; cv.u[1] = hi; pf0 = cv.s;                                     \
        lo[0] = pkfast(St[1][0], St[1][1]); lo[1] = pkfast(St[1][2], St[1][3]);     \
        hi[0] = pkfast(St[3][0], St[3][1]); hi[1] = pkfast(St[3][2], St[3][3]);     \
        cv.u[0] = lo; cv.u[1] = hi; pf1 = cv.s;                                     \
      }                                                                             \
      _Pragma("unroll")                                                             \
      for (int di = 0; di < 4; di++){                                               \
        Oc[mi][di] = __builtin_amdgcn_mfma_f32_16x16x32_bf16(vf[0][di], pf0, Oc[mi][di], 0, 0, 0); \
        Oc[mi][di] = __builtin_amdgcn_mfma_f32_16x16x32_bf16(vf[1][di], pf1, Oc[mi][di], 0, 0, 0); \
      }                                                                             \
    }                                                                               \
  }

  for (int i = 0; i < 4; i++){
    floatx4 Oc[4][4];
    float Olp[4] = {0.f, 0.f, 0.f, 0.f};
    #pragma unroll
    for (int mi = 0; mi < 4; mi++)
      #pragma unroll
      for (int di = 0; di < 4; di++) Oc[mi][di] = fzero;

    for (int kt = 0; kt < 32; kt += 2){
      TILE_BODY(0, i*32 + kt)
      TILE_BODY(1, i*32 + kt + 1)
    }

    // fold chunk: quad-reduce the per-lane partial row-sums, Of += Oc / l
    #pragma unroll
    for (int mi = 0; mi < 4; mi++){
      float l = Olp[mi];
      l += __shfl_xor(l, 16);
      l += __shfl_xor(l, 32);
      float inv = __builtin_amdgcn_rcpf(l);
      #pragma unroll
      for (int di = 0; di < 4; di++)
        #pragma unroll
        for (int r = 0; r < 4; r++) Of[mi][di][r] += Oc[mi][di][r] * inv;
    }
  }
#undef TILE_BODY

  // ctx[q][h*64+d] = Of/SP
  #pragma unroll
  for (int mi = 0; mi < 4; mi++){
    int q = sq0 + wq0 + mi*16 + l15;
    #pragma unroll
    for (int di = 0; di < 4; di++){
      uintx2 w;
      w[0] = pk2(Of[mi][di][0]*0.25f, Of[mi][di][1]*0.25f);
      w[1] = pk2(Of[mi][di][2]*0.25f, Of[mi][di][3]*0.25f);
      *(uintx2*)&ctx[(size_t)q*1024 + h*64 + di*16 + quad*4] = w;
    }
  }
}

// ---------------- host ----------------
extern "C" void kernel_launch(void* const* d_in, const int* in_sizes, int n_in,
                              void* d_out, int out_size, void* d_ws, size_t ws_size,
                              hipStream_t stream)
{
  (void)in_sizes; (void)n_in; (void)out_size; (void)ws_size;
  char* ws = (char*)d_ws;
  size_t off = 0;
  auto alloc = [&](size_t bytes) -> char* {
    char* p = ws + off;
    off = (off + bytes + 255) & ~(size_t)255;
    return p;
  };
  int* flag            = (int*)alloc(4);
  unsigned short* hsb  = (unsigned short*)alloc((size_t)8192*1024*2);
  unsigned short* wqt  = (unsigned short*)alloc((size_t)1024*1024*2);
  unsigned short* wkt  = (unsigned short*)alloc((size_t)1024*1024*2);
  unsigned short* wvt  = (unsigned short*)alloc((size_t)1024*1024*2);
  unsigned short* wot  = (unsigned short*)alloc((size_t)1024*1024*2);
  float* biasAll       = (float*)alloc(4096*4);                        // q,k,v,o contiguous
  unsigned short* Qb   = (unsigned short*)alloc((size_t)16*8192*64*2); // [h][s][d^sw] *Cs
  unsigned short* Kb   = (unsigned short*)alloc((size_t)16*8192*64*2); // [h][s][d^sw]
  unsigned short* Vb   = (unsigned short*)alloc((size_t)16*8192*64*2); // [h][d][s'^sw] permuted
  unsigned short* ctxb = (unsigned short*)alloc((size_t)8192*1024*2);  // [s][hd]

  k_detect<<<1, 256, 0, stream>>>((const unsigned*)d_in[0], flag);
  k_conv_bf16<<<4096, 256, 0, stream>>>(d_in[0], hsb, 8192*1024, flag);
  k_conv_wT4<<<dim3(32,32,4), 256, 0, stream>>>(d_in[1], d_in[3], d_in[5], d_in[7],
                                                wqt, wkt, wvt, wot, flag);
  k_conv_b4<<<16, 256, 0, stream>>>(d_in[2], d_in[4], d_in[6], d_in[8], biasAll, flag);

  const float Cs = 0.18033688011112042f;   // (1/8)*log2(e), folded into Q
  // fused QKV projection: N=3072
  k_gemm<3><<<dim3(64, 24), 256, 0, stream>>>(hsb, wqt, biasAll, Qb, Kb, Vb, nullptr, Cs);

  k_attn<<<512, 256, 0, stream>>>(Qb, Kb, Vb, ctxb);

  k_gemm<1><<<dim3(64, 8), 256, 0, stream>>>(ctxb, wot, biasAll + 3072, d_out,
                                             nullptr, nullptr, flag, 1.0f);
}

// Round 6
// 478.598 us; speedup vs baseline: 1.0446x; 1.0446x over previous
//
#include <hip/hip_runtime.h>

#define DEVINL __device__ __forceinline__

typedef __attribute__((ext_vector_type(8))) short short8;
typedef __attribute__((ext_vector_type(4))) float floatx4;
typedef __attribute__((ext_vector_type(2))) unsigned uintx2;

DEVINL unsigned short f2bf(float f){
  unsigned u = __builtin_bit_cast(unsigned, f);
  u += 0x7FFFu + ((u >> 16) & 1u);          // RNE
  return (unsigned short)(u >> 16);
}
DEVINL unsigned pk2(float a, float b){      // low16=bf16(a), high16=bf16(b)
  unsigned ua = __builtin_bit_cast(unsigned, a);
  unsigned ub = __builtin_bit_cast(unsigned, b);
  ua += 0x7FFFu + ((ua >> 16) & 1u);
  ub += 0x7FFFu + ((ub >> 16) & 1u);
  return (ua >> 16) | (ub & 0xFFFF0000u);
}
// round-half-up bf16 pack of (a,b) via v_perm (proven numerics; do NOT use
// v_cvt_pk_bf16_f32 here -- it truncates and fails the absmax threshold)
DEVINL unsigned pkfast(float a, float b){
  unsigned ua = __builtin_bit_cast(unsigned, a) + 0x8000u;
  unsigned ub = __builtin_bit_cast(unsigned, b) + 0x8000u;
  return __builtin_amdgcn_perm(ub, ua, 0x07060302u);
}
DEVINL float bf2f(unsigned short h){
  unsigned u = ((unsigned)h) << 16;
  return __builtin_bit_cast(float, u);
}
DEVINL void gload_lds16(const void* g, void* l){
  __builtin_amdgcn_global_load_lds((const __attribute__((address_space(1))) void*)g,
                                   (__attribute__((address_space(3))) void*)l, 16, 0, 0);
}
// key permutation: St C-layout register <-> PV B-operand k' index
DEVINL int perm2(int k){
  return (((k >> 4) & 1) << 5) | (((k >> 2) & 3) << 3) | (((k >> 5) & 1) << 2) | (k & 3);
}

// ---------------- dtype detector ----------------
__global__ void k_detect(const unsigned* __restrict__ w, int* __restrict__ flag){
  __shared__ int cnt;
  if (threadIdx.x == 0) cnt = 0;
  __syncthreads();
  int c = 0;
  for (int i = threadIdx.x; i < 1024; i += 256){
    unsigned e = (w[i] >> 7) & 0xFFu;
    c += (e >= 120u && e <= 132u) ? 1 : 0;
  }
  atomicAdd(&cnt, c);
  __syncthreads();
  if (threadIdx.x == 0) *flag = (cnt > 512) ? 1 : 0;
}

// ---------------- conversions ----------------
__global__ void k_conv_bf16(const void* __restrict__ src, unsigned short* __restrict__ dst,
                            int n, const int* __restrict__ flag){
  int i = (blockIdx.x * 256 + threadIdx.x) * 8;
  if (i >= n) return;
  if (*flag){
    ((uint4*)dst)[i >> 3] = ((const uint4*)src)[i >> 3];
  } else {
    const float* s = (const float*)src;
    short8 v;
    #pragma unroll
    for (int j = 0; j < 8; j++) v[j] = (short)f2bf(s[i + j]);
    *(short8*)(dst + i) = v;
  }
}

// 4 weights [K][N] -> [N][K] bf16, one launch (z selects matrix)
__global__ void k_conv_wT4(const void* __restrict__ s0, const void* __restrict__ s1,
                           const void* __restrict__ s2, const void* __restrict__ s3,
                           unsigned short* __restrict__ d0, unsigned short* __restrict__ d1,
                           unsigned short* __restrict__ d2, unsigned short* __restrict__ d3,
                           const int* __restrict__ flag){
  __shared__ float tile[32][33];
  const void* src; unsigned short* dst;
  switch (blockIdx.z){
    case 0: src = s0; dst = d0; break;
    case 1: src = s1; dst = d1; break;
    case 2: src = s2; dst = d2; break;
    default: src = s3; dst = d3; break;
  }
  const int tx = threadIdx.x & 31, ty = threadIdx.x >> 5;
  const int bx = blockIdx.x, by = blockIdx.y;
  const int isbf = *flag;
  #pragma unroll
  for (int r = 0; r < 32; r += 8){
    int k = by*32 + ty + r, n = bx*32 + tx;
    float v = isbf ? bf2f(((const unsigned short*)src)[k*1024 + n])
                   : ((const float*)src)[k*1024 + n];
    tile[ty + r][tx] = v;
  }
  __syncthreads();
  #pragma unroll
  for (int r = 0; r < 32; r += 8){
    int n = bx*32 + ty + r, k = by*32 + tx;
    dst[n*1024 + k] = f2bf(tile[tx][ty + r]);
  }
}

// 4 biases -> one contiguous float[4096]
__global__ void k_conv_b4(const void* __restrict__ s0, const void* __restrict__ s1,
                          const void* __restrict__ s2, const void* __restrict__ s3,
                          float* __restrict__ dst, const int* __restrict__ flag){
  int i = blockIdx.x * 256 + threadIdx.x;
  if (i >= 4096) return;
  int z = i >> 10, j = i & 1023;
  const void* s = (z == 0) ? s0 : (z == 1) ? s1 : (z == 2) ? s2 : s3;
  dst[i] = (*flag) ? bf2f(((const unsigned short*)s)[j]) : ((const float*)s)[j];
}

// ---------------- m97-style bf16 GEMM, A[M,K] x Bt[N,K]^T + bias ----------------
// MODE 3: fused QKV, N=3072. n>>10 selects dst:
//   0 -> Q [h][s][d^sw] (*scale)   1 -> K [h][s][d^sw]   2 -> V [h][d][s'^sw] (key-permuted)
//   where ^sw = XOR of the 16B-chunk index with (row&7) -- pre-swizzled for LDS.
// MODE 1: dst = C0, [m][n]; fp32 or bf16 per *flagp
template<int MODE>
__global__ __launch_bounds__(256, 2) void k_gemm(
    const unsigned short* __restrict__ A, const unsigned short* __restrict__ Bt,
    const float* __restrict__ bias, void* __restrict__ C0, void* __restrict__ C1,
    void* __restrict__ C2, const int* __restrict__ flagp, float scale)
{
  const int K = 1024;
  __shared__ __align__(16) unsigned short As[128*32];
  __shared__ __align__(16) unsigned short Bs[128*32];
  const int tid = threadIdx.x;
  const int lane = tid & 63, wave = tid >> 6;
  const int quad = lane >> 4, l15 = lane & 15;
  const int m0 = blockIdx.x * 128, n0 = blockIdx.y * 128;
  const int wm = (wave >> 1) * 64, wn = (wave & 1) * 64;
  const floatx4 fzero = {0.f, 0.f, 0.f, 0.f};
  floatx4 acc[4][4];
  #pragma unroll
  for (int i = 0; i < 4; i++)
    #pragma unroll
    for (int j = 0; j < 4; j++) acc[i][j] = fzero;

  for (int k0 = 0; k0 < K; k0 += 32){
    __syncthreads();
    #pragma unroll
    for (int rep = 0; rep < 2; rep++){
      int idx = tid + rep*256;
      int row = idx >> 2, c = idx & 3;
      gload_lds16(A  + (size_t)(m0 + row)*K + (k0 + c*8), &As[idx*8]);
      gload_lds16(Bt + (size_t)(n0 + row)*K + (k0 + c*8), &Bs[idx*8]);
    }
    asm volatile("s_waitcnt vmcnt(0)" ::: "memory");
    __syncthreads();
    short8 af[4], bf[4];
    #pragma unroll
    for (int i = 0; i < 4; i++) af[i] = *(const short8*)&As[(wm + i*16 + l15)*32 + quad*8];
    #pragma unroll
    for (int j = 0; j < 4; j++) bf[j] = *(const short8*)&Bs[(wn + j*16 + l15)*32 + quad*8];
    #pragma unroll
    for (int i = 0; i < 4; i++)
      #pragma unroll
      for (int j = 0; j < 4; j++)
        acc[i][j] = __builtin_amdgcn_mfma_f32_16x16x32_bf16(af[i], bf[j], acc[i][j], 0, 0, 0);
  }

  float bs[4];
  #pragma unroll
  for (int j = 0; j < 4; j++) bs[j] = bias[n0 + wn + j*16 + l15];
  const int useBf = (MODE == 1) ? *flagp : 1;
  #pragma unroll
  for (int i = 0; i < 4; i++){
    #pragma unroll
    for (int j = 0; j < 4; j++){
      int n = n0 + wn + j*16 + l15;
      #pragma unroll
      for (int r = 0; r < 4; r++){
        int m = m0 + wm + i*16 + quad*4 + r;      // C/D: col=lane&15, row=quad*4+reg
        float v = acc[i][j][r] + bs[j];
        if (MODE == 3){
          int sel = n >> 10, nn = n & 1023;       // wave-uniform per (i,j)
          if (sel == 0){
            int dd = (nn & 63) ^ ((m & 7) << 3);  // pre-swizzle chunk by s&7
            ((unsigned short*)C0)[((size_t)(nn >> 6)*8192 + m)*64 + dd] = f2bf(v * scale);
          } else if (sel == 1){
            int dd = (nn & 63) ^ ((m & 7) << 3);
            ((unsigned short*)C1)[((size_t)(nn >> 6)*8192 + m)*64 + dd] = f2bf(v);
          } else {
            int s2 = perm2(m & 63) ^ ((nn & 7) << 3);  // key-perm then swizzle by d&7
            ((unsigned short*)C2)[(size_t)nn*8192 + (m & ~63) + s2] = f2bf(v);
          }
        } else {
          if (useBf) ((unsigned short*)C0)[(size_t)m*1024 + n] = f2bf(v);
          else       ((float*)C0)[(size_t)m*1024 + n] = v;
        }
      }
    }
  }
}

// ---------------- ring attention: 256q block, 64q/wave ----------------
// R0-proven two-phase structure (311us) with two additive changes:
//  (a) zero-VALU LDS addressing: row&7 == l15&7 for every K/V fragment row, so all
//      fragment reads are per-lane base + compile-time immediate. KV combined array
//      (R5-proven staging layout), kt unrolled x2 for static buffer parity.
//  (b) phase-stagger: the 2 co-resident blocks/CU run identical periodic code and
//      phase-lock (R0 counters: MfmaUtil 44 + VALUBusy 49 ~ sum = wall, i.e. ZERO
//      cross-wave pipe overlap). A one-time half-tile s_sleep for half the blocks
//      breaks the symmetry so one wave's MFMA cluster overlaps the other's exp/pack.
// REFUTED previously: occupancy>2 blocks/CU (spills), setprio (fence cost), per-mi
// fused QK/PV + vf hoist (spills: WRITE 26->79MB).
__global__ __launch_bounds__(256, 2) void k_attn(
    const unsigned short* __restrict__ Qg, const unsigned short* __restrict__ Kg,
    const unsigned short* __restrict__ Vg, unsigned short* __restrict__ ctx)
{
  __shared__ __align__(16) unsigned short Qs[256*64];       // 32KB
  __shared__ __align__(16) unsigned short KV[2*64*64*2];    // K bufs [0,16KB), V bufs [16KB,32KB)
  const int tid = threadIdx.x, lane = tid & 63, wave = tid >> 6;
  const int quad = lane >> 4, l15 = lane & 15;
  const int bid = blockIdx.x;
  const int xcd = bid & 7, slot = bid >> 3;
  const int h = xcd*2 + (slot >> 5);
  const int rem = slot & 31, rchunk = rem >> 3, qt = rem & 7;
  const int sq0 = rchunk*2048 + qt*256;
  const char* Qbase = (const char*)(Qg + (size_t)h*8192*64 + (size_t)sq0*64);
  const char* Kbase = (const char*)(Kg + (size_t)h*8192*64);     // [s][d^sw] rows 128B
  const char* Vbase = (const char*)(Vg + (size_t)h*8192*64);     // [d][s'^sw] rows 16KB
  const int wq0 = wave * 64;
  const floatx4 fzero = {0.f, 0.f, 0.f, 0.f};

  // per-thread fixed staging offsets
  const int idx0 = tid, idx1 = tid + 256;
  const size_t voff0 = (size_t)(idx0 >> 3)*16384 + (idx0 & 7)*16;
  const size_t voff1 = (size_t)(idx1 >> 3)*16384 + (idx1 & 7)*16;

  auto stage = [&](int buf, int kvs){
    const char* Kt = Kbase + (size_t)kvs*128;
    const char* Vt = Vbase + (size_t)kvs*2;
    char* kd = (char*)KV + buf*8192;
    char* vd = (char*)KV + 16384 + buf*8192;
    gload_lds16(Kt + idx0*16, kd + idx0*16);
    gload_lds16(Kt + idx1*16, kd + idx1*16);
    gload_lds16(Vt + voff0, vd + idx0*16);
    gload_lds16(Vt + voff1, vd + idx1*16);
  };

  // stage Q (straight 32KB copy) + first K/V tile
  #pragma unroll
  for (int rep = 0; rep < 8; rep++){
    int idx = tid + rep*256;
    gload_lds16(Qbase + idx*16, (char*)Qs + idx*16);
  }
  stage(0, rchunk*2048);

  // phase-stagger: half-tile sleep for half the blocks, while the staging flies.
  // (bid ^ (bid>>8)) & 1 differs within a pair under both plausible CU pairings
  // ((2i,2i+1) and (i,i+256)).
  if ((bid ^ (bid >> 8)) & 1)
    asm volatile("s_sleep 45");

  // per-lane LDS fragment base addresses (row&7 == l15&7 for all fragment rows);
  // every K/V read below is base + compile-time immediate offset.
  const int swz0 = ((0*4 + quad) ^ (l15 & 7)) * 16;
  const int swz1 = ((1*4 + quad) ^ (l15 & 7)) * 16;
  const char* kB0 = (const char*)KV + l15*128 + swz0;            // + CUR*8192 + ni*2048
  const char* kB1 = (const char*)KV + l15*128 + swz1;
  const char* vB0 = (const char*)KV + 16384 + l15*128 + swz0;    // + CUR*8192 + di*2048
  const char* vB1 = (const char*)KV + 16384 + l15*128 + swz1;

  asm volatile("s_waitcnt vmcnt(0)" ::: "memory");
  __syncthreads();

  short8 qf[4][2];                                     // B-operand fragments (persistent)
  #pragma unroll
  for (int mi = 0; mi < 4; mi++)
    #pragma unroll
    for (int ks = 0; ks < 2; ks++){
      int row = wq0 + mi*16 + l15;
      qf[mi][ks] = *(const short8*)&Qs[row*64 + (((ks*4 + quad) ^ (row & 7)))*8];
    }

  short8 ones;
  #pragma unroll
  for (int j = 0; j < 8; j++) ones[j] = (short)0x3F80;  // bf16 1.0

  floatx4 Of[4][4];
  #pragma unroll
  for (int mi = 0; mi < 4; mi++)
    #pragma unroll
    for (int di = 0; di < 4; di++) Of[mi][di] = fzero;

// one K/V tile, static buffer parity CUR (R0 two-phase compute, imm-offset reads)
#define TILE_BODY(CUR, TT)                                                            \
  {                                                                                   \
    asm volatile("s_waitcnt vmcnt(0)" ::: "memory");  /* tile TT landed */            \
    __syncthreads();                                  /* prev readers done */         \
    if ((TT) < 127){                                                                  \
      int t1 = (TT) + 1;                                                              \
      int kvs = ((rchunk + (t1 >> 5)) & 3)*2048 + (t1 & 31)*64;                       \
      stage((CUR) ^ 1, kvs);                          /* async, lands in compute */   \
    }                                                                                 \
    short8 pf[4][2];                                                                  \
    _Pragma("unroll")                                                                 \
    for (int mi = 0; mi < 4; mi++){                                                   \
      floatx4 St[4];                                                                  \
      _Pragma("unroll")                                                               \
      for (int ni = 0; ni < 4; ni++) St[ni] = fzero;                                  \
      _Pragma("unroll")                                                               \
      for (int ni = 0; ni < 4; ni++){                                                 \
        short8 kf0 = *(const short8*)(kB0 + (CUR)*8192 + ni*2048);                    \
        short8 kf1 = *(const short8*)(kB1 + (CUR)*8192 + ni*2048);                    \
        St[ni] = __builtin_amdgcn_mfma_f32_16x16x32_bf16(kf0, qf[mi][0], St[ni], 0, 0, 0); \
        St[ni] = __builtin_amdgcn_mfma_f32_16x16x32_bf16(kf1, qf[mi][1], St[ni], 0, 0, 0); \
      }                                                                               \
      _Pragma("unroll")                                                               \
      for (int ni = 0; ni < 4; ni++)                                                  \
        _Pragma("unroll")                                                             \
        for (int r = 0; r < 4; r++)                                                   \
          St[ni][r] = __builtin_amdgcn_exp2f(St[ni][r]);                              \
      _Pragma("unroll")                                                               \
      for (int ks = 0; ks < 2; ks++){                                                 \
        uintx2 lo, hi;  /* 8 shorts: e[ks][0..3], e[ks+2][0..3] */                    \
        lo[0] = pkfast(St[ks  ][0], St[ks  ][1]);                                     \
        lo[1] = pkfast(St[ks  ][2], St[ks  ][3]);                                     \
        hi[0] = pkfast(St[2+ks][0], St[2+ks][1]);                                     \
        hi[1] = pkfast(St[2+ks][2], St[2+ks][3]);                                     \
        union { uintx2 u[2]; short8 s; } cv;                                          \
        cv.u[0] = lo; cv.u[1] = hi;                                                   \
        pf[mi][ks] = cv.s;                                                            \
      }                                                                               \
    }                                                                                 \
    _Pragma("unroll")                                                                 \
    for (int ks = 0; ks < 2; ks++){                                                   \
      _Pragma("unroll")                                                               \
      for (int di = 0; di < 4; di++){                                                 \
        short8 vf = *(const short8*)((ks ? vB1 : vB0) + (CUR)*8192 + di*2048);        \
        _Pragma("unroll")                                                             \
        for (int mi = 0; mi < 4; mi++)                                                \
          Oc[mi][di] = __builtin_amdgcn_mfma_f32_16x16x32_bf16(vf, pf[mi][ks], Oc[mi][di], 0, 0, 0); \
      }                                                                               \
      _Pragma("unroll")                                                               \
      for (int mi = 0; mi < 4; mi++)                                                  \
        Ol[mi] = __builtin_amdgcn_mfma_f32_16x16x32_bf16(ones, pf[mi][ks], Ol[mi], 0, 0, 0); \
    }                                                                                 \
  }

  for (int i = 0; i < 4; i++){
    floatx4 Oc[4][4], Ol[4];
    #pragma unroll
    for (int mi = 0; mi < 4; mi++){
      Ol[mi] = fzero;
      #pragma unroll
      for (int di = 0; di < 4; di++) Oc[mi][di] = fzero;
    }

    for (int kt = 0; kt < 32; kt += 2){
      TILE_BODY(0, i*32 + kt)
      TILE_BODY(1, i*32 + kt + 1)
    }

    // fold chunk: Of += Oc / l   (Ol rows all equal the complete per-q sum)
    #pragma unroll
    for (int mi = 0; mi < 4; mi++){
      float inv = __builtin_amdgcn_rcpf(Ol[mi][0]);
      #pragma unroll
      for (int di = 0; di < 4; di++)
        #pragma unroll
        for (int r = 0; r < 4; r++) Of[mi][di][r] += Oc[mi][di][r] * inv;
    }
  }
#undef TILE_BODY

  // ctx[q][h*64+d] = Of/SP
  #pragma unroll
  for (int mi = 0; mi < 4; mi++){
    int q = sq0 + wq0 + mi*16 + l15;
    #pragma unroll
    for (int di = 0; di < 4; di++){
      uintx2 w;
      w[0] = pk2(Of[mi][di][0]*0.25f, Of[mi][di][1]*0.25f);
      w[1] = pk2(Of[mi][di][2]*0.25f, Of[mi][di][3]*0.25f);
      *(uintx2*)&ctx[(size_t)q*1024 + h*64 + di*16 + quad*4] = w;
    }
  }
}

// ---------------- host ----------------
extern "C" void kernel_launch(void* const* d_in, const int* in_sizes, int n_in,
                              void* d_out, int out_size, void* d_ws, size_t ws_size,
                              hipStream_t stream)
{
  (void)in_sizes; (void)n_in; (void)out_size; (void)ws_size;
  char* ws = (char*)d_ws;
  size_t off = 0;
  auto alloc = [&](size_t bytes) -> char* {
    char* p = ws + off;
    off = (off + bytes + 255) & ~(size_t)255;
    return p;
  };
  int* flag            = (int*)alloc(4);
  unsigned short* hsb  = (unsigned short*)alloc((size_t)8192*1024*2);
  unsigned short* wqt  = (unsigned short*)alloc((size_t)1024*1024*2);
  unsigned short* wkt  = (unsigned short*)alloc((size_t)1024*1024*2);
  unsigned short* wvt  = (unsigned short*)alloc((size_t)1024*1024*2);
  unsigned short* wot  = (unsigned short*)alloc((size_t)1024*1024*2);
  float* biasAll       = (float*)alloc(4096*4);                        // q,k,v,o contiguous
  unsigned short* Qb   = (unsigned short*)alloc((size_t)16*8192*64*2); // [h][s][d^sw] *Cs
  unsigned short* Kb   = (unsigned short*)alloc((size_t)16*8192*64*2); // [h][s][d^sw]
  unsigned short* Vb   = (unsigned short*)alloc((size_t)16*8192*64*2); // [h][d][s'^sw] permuted
  unsigned short* ctxb = (unsigned short*)alloc((size_t)8192*1024*2);  // [s][hd]

  k_detect<<<1, 256, 0, stream>>>((const unsigned*)d_in[0], flag);
  k_conv_bf16<<<4096, 256, 0, stream>>>(d_in[0], hsb, 8192*1024, flag);
  k_conv_wT4<<<dim3(32,32,4), 256, 0, stream>>>(d_in[1], d_in[3], d_in[5], d_in[7],
                                                wqt, wkt, wvt, wot, flag);
  k_conv_b4<<<16, 256, 0, stream>>>(d_in[2], d_in[4], d_in[6], d_in[8], biasAll, flag);

  const float Cs = 0.18033688011112042f;   // (1/8)*log2(e), folded into Q
  // fused QKV projection: N=3072
  k_gemm<3><<<dim3(64, 24), 256, 0, stream>>>(hsb, wqt, biasAll, Qb, Kb, Vb, nullptr, Cs);

  k_attn<<<512, 256, 0, stream>>>(Qb, Kb, Vb, ctxb);

  k_gemm<1><<<dim3(64, 8), 256, 0, stream>>>(ctxb, wot, biasAll + 3072, d_out,
                                             nullptr, nullptr, flag, 1.0f);
}